// Round 16
// baseline (1461.937 us; speedup 1.0000x reference)
//
#include <hip/hip_runtime.h>

#define B_ 256
#define S_ 512
#define V_ 50000
#define F_ 64
#define H_ 256

typedef _Float16 f16;
typedef _Float16 f16x2 __attribute__((ext_vector_type(2)));
typedef _Float16 f16x4 __attribute__((ext_vector_type(4)));
typedef _Float16 f16x8 __attribute__((ext_vector_type(8)));
typedef float f32x4 __attribute__((ext_vector_type(4)));

#define MFMA(a, b, c) __builtin_amdgcn_mfma_f32_16x16x32_f16((a), (b), (c), 0, 0, 0)

__device__ __forceinline__ f16x8 cvt8(const float4 a, const float4 b) {
    f16x8 v;
    v[0] = (f16)a.x; v[1] = (f16)a.y; v[2] = (f16)a.z; v[3] = (f16)a.w;
    v[4] = (f16)b.x; v[5] = (f16)b.y; v[6] = (f16)b.z; v[7] = (f16)b.w;
    return v;
}

// tanh(x) = 1 - 2/(1+e^2x); IEEE-safe at +/-inf.
__device__ __forceinline__ float fast_tanh(float x) {
    float e = __expf(2.f * x);
    float r = __builtin_amdgcn_rcpf(e + 1.f);
    return __builtin_fmaf(-2.f, r, 1.f);
}

__device__ __forceinline__ f32x4 cvt4f(const f16x4 v) {
    f32x4 r; r[0] = (float)v[0]; r[1] = (float)v[1]; r[2] = (float)v[2]; r[3] = (float)v[3];
    return r;
}
__device__ __forceinline__ f16x4 pack4(const f32x4 a, const f32x4 b) {
    f16x4 r; r[0] = (f16)(a[0] + b[0]); r[1] = (f16)(a[1] + b[1]);
    r[2] = (f16)(a[2] + b[2]); r[3] = (f16)(a[3] + b[3]);
    return r;
}
__device__ __forceinline__ f16x4 tanh4(const f32x4 a, const f32x4 b) {
    f16x4 r;
#pragma unroll
    for (int i = 0; i < 4; ++i) r[i] = (f16)fast_tanh(a[i] + b[i]);
    return r;
}

// ---------------------------------------------------------------------------
// K0: zero flags: prodf[16][8] @0, consf[16] @128, projf[16][8] @160.
// ---------------------------------------------------------------------------
__global__ void k_init_flags(int* flags) {
    flags[threadIdx.x] = 0;   // 512 threads cover 288 used + slack
}

// ---------------------------------------------------------------------------
// K1: T[v][n] = sum_f feat[v][f] * Wih0[n][f] + (bih0[n]+bhh0[n]); f16 out.
// ---------------------------------------------------------------------------
__global__ __launch_bounds__(512) void k_vocab_proj(
    const float* __restrict__ feat, const float* __restrict__ Wih,
    const float* __restrict__ bi, const float* __restrict__ bh,
    f16* __restrict__ T)
{
    __shared__ char Wl[256 * 128];
    __shared__ char Xl[16 * 128];
    const int tid = threadIdx.x;
    {
        const int n = tid >> 1, k0 = (tid & 1) << 5;
#pragma unroll
        for (int k = k0; k < k0 + 32; k += 8) {
            float4 a = *(const float4*)(Wih + n * F_ + k);
            float4 b = *(const float4*)(Wih + n * F_ + k + 4);
            *(f16x8*)(Wl + n * 128 + (((k >> 3) ^ (n & 7)) << 4)) = cvt8(a, b);
        }
    }
    const int v0 = blockIdx.x * 16;
    {
        const int m = tid >> 5, k = (tid & 31) << 1;
        float2 a = *(const float2*)(feat + (v0 + m) * F_ + k);
        f16x2 v; v[0] = (f16)a.x; v[1] = (f16)a.y;
        *(f16x2*)(Xl + m * 128 + ((((k >> 3) ^ (m & 7)) << 4) | ((k & 7) << 1))) = v;
    }
    __syncthreads();
    const int lane = tid & 63, w = tid >> 6;
    const int q = lane & 15, g = lane >> 4;
#pragma unroll
    for (int nt = 0; nt < 2; ++nt) {
        const int n0 = w * 32 + nt * 16;
        const int nrow = n0 + q;
        float4 b1 = *(const float4*)(bi + n0 + g * 4);
        float4 b2 = *(const float4*)(bh + n0 + g * 4);
        f32x4 acc = {b1.x + b2.x, b1.y + b2.y, b1.z + b2.z, b1.w + b2.w};
#pragma unroll
        for (int kb = 0; kb < 2; ++kb) {
            f16x8 a = *(const f16x8*)(Wl + nrow * 128 + (((kb * 4 + g) ^ (nrow & 7)) << 4));
            f16x8 b = *(const f16x8*)(Xl + q * 128 + (((kb * 4 + g) ^ (q & 7)) << 4));
            acc = MFMA(a, b, acc);
        }
        f16x4 o; o[0] = (f16)acc[0]; o[1] = (f16)acc[1]; o[2] = (f16)acc[2]; o[3] = (f16)acc[3];
        *(f16x4*)(T + (size_t)(v0 + q) * H_ + n0 + g * 4) = o;
    }
}

// ---------------------------------------------------------------------------
// K2: three-role pipelined RNN, 48 WGs x 512 thr (8 waves = 2/SIMD).
//   WGs 0-15  PRODUCER (gr=wg): pure recur0, 8-wave 2tt (R12-proven body).
//     h0_t -> LDS dbuf + 128-slot global ring. Flag/8; back-pressure vs
//     consumer every 16 (margin 80 < ring 128 even with projector lag).
//   WGs 32-47 PROJECTOR (gr=wg-32): NO recurrence, NO barriers. All 8 waves
//     compute p_s = b1 + Wih1 @ h0_s (2tt each) from ring reads held in a
//     2-DEEP register prefetch (HFa/HFb: ~2 iterations of vmcnt slack;
//     R13's failure was <1 step of slack inside a serial loop). p -> pst
//     global stream [b][t][n]; per-wave flag (release, drains p stores)
//     every 8 steps.
//   WGs 16-31 CONSUMER (gr=wg-16): pure recur1, structurally IDENTICAL to
//     the producer (8-wave 2tt), with the additive p term register-
//     prefetched 2 steps ahead from pst (R11-proven pattern). Spins on
//     projector flags every 8 steps. Writes only final h1.
// Sync: producer -> projector -> consumer (acyclic); producer throttles
// only on consumer progress. Deadlock-free; max producer-projector skew
// ~100 < ring 128.
// ---------------------------------------------------------------------------
__global__ __launch_bounds__(512) __attribute__((amdgpu_waves_per_eu(2, 2)))
void k_rnn3p(
    const f16* __restrict__ T, const int* __restrict__ idx,
    const float* __restrict__ Whh0, const float* __restrict__ Wih1,
    const float* __restrict__ bih1, const float* __restrict__ bhh1,
    const float* __restrict__ Whh1,
    f16* __restrict__ h0ring, f16* __restrict__ pst,
    int* flags, f16* __restrict__ h1out)
{
    __shared__ char hb[2][8192];   // producer: h0 dbuf | consumer: h1 dbuf
    const int wg = blockIdx.x;
    const int tid = threadIdx.x, lane = tid & 63, w = tid >> 6;
    const int q = lane & 15, gl = lane >> 4;
    const int swz = (q & 7) << 4;

    int rbase[2];
#pragma unroll
    for (int p2 = 0; p2 < 2; ++p2)
        rbase[p2] = q * 512 + ((p2 * 64 + gl * 16) ^ swz);

    int* prodf = flags;          // [16][8] producer per-wave flags
    int* consf = flags + 128;    // [16]    consumer progress
    int* projf = flags + 160;    // [16][8] projector per-wave flags
    const int gr = (wg < 16) ? wg : ((wg < 32) ? wg - 16 : wg - 32);
    const int brow = gr * 16 + q;
    f16* ringg = h0ring + ((size_t)gr << 19);   // 128 slots x 4096 f16
    const int nb2 = w * 32;

#define FRD(kb_, RD_) (*(const f16x8*)(hb[RD_] + rbase[(kb_) & 1] + (((kb_) >> 1) * 128)))
#define STEP_BAR() do { \
        asm volatile("s_waitcnt lgkmcnt(0)" ::: "memory"); \
        __builtin_amdgcn_s_barrier(); \
    } while (0)

    if (wg < 16) {
        // ================= PRODUCER (R12-proven body) =================
        int wb2[2];
#pragma unroll
        for (int tt = 0; tt < 2; ++tt)
            wb2[tt] = q * 512 + (((nb2 + tt * 16 + gl * 4) * 2) ^ swz);

        f16x8 wA[2][8];
#pragma unroll
        for (int tt = 0; tt < 2; ++tt) {
            const int n = nb2 + tt * 16 + q;
#pragma unroll
            for (int kb = 0; kb < 8; ++kb) {
                const int o = n * H_ + kb * 32 + gl * 8;
                wA[tt][kb] = cvt8(*(const float4*)(Whh0 + o), *(const float4*)(Whh0 + o + 4));
            }
        }
        {   f32x4 z = {0.f, 0.f, 0.f, 0.f}; *(f32x4*)(hb[1] + tid * 16) = z; }
        const int* idxr = idx + brow * S_;
        int* myflag = prodf + gr * 8 + w;
        f16x4 xa[2], xb[2];
        {
            const size_t r0 = (size_t)idxr[0] * H_, r1 = (size_t)idxr[1] * H_;
#pragma unroll
            for (int tt = 0; tt < 2; ++tt) {
                xa[tt] = *(const f16x4*)(T + r0 + nb2 + tt * 16 + gl * 4);
                xb[tt] = *(const f16x4*)(T + r1 + nb2 + tt * 16 + gl * 4);
            }
        }
        int iA = idxr[2], iB = idxr[3];
        __syncthreads();

#define PBODY(XV, ID, RD, WR, T_) do {                                          \
        if (((T_) & 15) == 0) {   /* back-pressure: margin 80 < ring 128 */     \
            int v_;                                                             \
            do { v_ = __hip_atomic_load(consf + gr, __ATOMIC_RELAXED,           \
                                        __HIP_MEMORY_SCOPE_AGENT);              \
            } while ((T_) - v_ > 80);                                           \
        }                                                                       \
        f16x8 bf0 = FRD(0, RD), bf1 = FRD(1, RD), bf2 = FRD(2, RD),             \
              bf3 = FRD(3, RD), bf4 = FRD(4, RD), bf5 = FRD(5, RD),             \
              bf6 = FRD(6, RD), bf7 = FRD(7, RD);                               \
        f32x4 aL[2], aH[2];                                                     \
        _Pragma("unroll")                                                       \
        for (int tt = 0; tt < 2; ++tt) {                                        \
            aL[tt] = cvt4f(XV[tt]);                                             \
            aH[tt][0] = 0.f; aH[tt][1] = 0.f; aH[tt][2] = 0.f; aH[tt][3] = 0.f; \
        }                                                                       \
        if ((((T_) & 7) == 0) && lane == 0)                                     \
            __hip_atomic_store(myflag, (T_), __ATOMIC_RELEASE,                  \
                               __HIP_MEMORY_SCOPE_AGENT);                       \
        {                                                                       \
            const size_t rr = (size_t)ID * H_;                                  \
            _Pragma("unroll")                                                   \
            for (int tt = 0; tt < 2; ++tt)                                      \
                XV[tt] = *(const f16x4*)(T + rr + nb2 + tt * 16 + gl * 4);      \
            const int t4 = ((T_) + 4 < S_) ? (T_) + 4 : S_ - 1;                 \
            ID = idxr[t4];                                                      \
        }                                                                       \
        _Pragma("unroll")                                                       \
        for (int tt = 0; tt < 2; ++tt) {                                        \
            aL[tt] = MFMA(wA[tt][0], bf0, aL[tt]);                              \
            aH[tt] = MFMA(wA[tt][4], bf4, aH[tt]);                              \
            aL[tt] = MFMA(wA[tt][1], bf1, aL[tt]);                              \
            aH[tt] = MFMA(wA[tt][5], bf5, aH[tt]);                              \
            aL[tt] = MFMA(wA[tt][2], bf2, aL[tt]);                              \
            aH[tt] = MFMA(wA[tt][6], bf6, aH[tt]);                              \
            aL[tt] = MFMA(wA[tt][3], bf3, aL[tt]);                              \
            aH[tt] = MFMA(wA[tt][7], bf7, aH[tt]);                              \
        }                                                                       \
        {                                                                       \
            f16* rp = ringg + (size_t)((T_) & 127) * 4096 + q * 256 + nb2;      \
            _Pragma("unroll")                                                   \
            for (int tt = 0; tt < 2; ++tt) {                                    \
                f16x4 hv = tanh4(aL[tt], aH[tt]);                               \
                *(f16x4*)(hb[WR] + wb2[tt]) = hv;                               \
                *(f16x4*)(rp + tt * 16 + gl * 4) = hv;                          \
            }                                                                   \
        }                                                                       \
        STEP_BAR();                                                             \
    } while (0)

        // peel t=0 (from zero state)
        {
            f16x8 bf0 = FRD(0, 1), bf1 = FRD(1, 1), bf2 = FRD(2, 1), bf3 = FRD(3, 1),
                  bf4 = FRD(4, 1), bf5 = FRD(5, 1), bf6 = FRD(6, 1), bf7 = FRD(7, 1);
            f32x4 aL[2], aH[2];
#pragma unroll
            for (int tt = 0; tt < 2; ++tt) {
                aL[tt] = cvt4f(xa[tt]);
                aH[tt][0] = 0.f; aH[tt][1] = 0.f; aH[tt][2] = 0.f; aH[tt][3] = 0.f;
            }
            {
                const size_t rr = (size_t)iA * H_;
#pragma unroll
                for (int tt = 0; tt < 2; ++tt)
                    xa[tt] = *(const f16x4*)(T + rr + nb2 + tt * 16 + gl * 4);
                iA = idxr[4];
            }
#pragma unroll
            for (int tt = 0; tt < 2; ++tt) {
                aL[tt] = MFMA(wA[tt][0], bf0, aL[tt]);
                aH[tt] = MFMA(wA[tt][4], bf4, aH[tt]);
                aL[tt] = MFMA(wA[tt][1], bf1, aL[tt]);
                aH[tt] = MFMA(wA[tt][5], bf5, aH[tt]);
                aL[tt] = MFMA(wA[tt][2], bf2, aL[tt]);
                aH[tt] = MFMA(wA[tt][6], bf6, aH[tt]);
                aL[tt] = MFMA(wA[tt][3], bf3, aL[tt]);
                aH[tt] = MFMA(wA[tt][7], bf7, aH[tt]);
            }
            f16* rp = ringg + q * 256 + nb2;
#pragma unroll
            for (int tt = 0; tt < 2; ++tt) {
                f16x4 hv = tanh4(aL[tt], aH[tt]);
                *(f16x4*)(hb[0] + wb2[tt]) = hv;
                *(f16x4*)(rp + tt * 16 + gl * 4) = hv;
            }
            STEP_BAR();
        }
        for (int t = 1; t < 511; t += 2) {
            PBODY(xb, iB, 0, 1, t);
            PBODY(xa, iA, 1, 0, t + 1);
        }
        PBODY(xb, iB, 0, 1, 511);
        if (lane == 0)
            __hip_atomic_store(myflag, 516, __ATOMIC_RELEASE, __HIP_MEMORY_SCOPE_AGENT);
#undef PBODY
    } else if (wg < 32) {
        // ================= CONSUMER (pure recur1, producer-shaped) =========
        int wb2[2];
#pragma unroll
        for (int tt = 0; tt < 2; ++tt)
            wb2[tt] = q * 512 + (((nb2 + tt * 16 + gl * 4) * 2) ^ swz);

        f16x8 wC[2][8];
#pragma unroll
        for (int tt = 0; tt < 2; ++tt) {
            const int n = nb2 + tt * 16 + q;
#pragma unroll
            for (int kb = 0; kb < 8; ++kb) {
                const int o = n * H_ + kb * 32 + gl * 8;
                wC[tt][kb] = cvt8(*(const float4*)(Whh1 + o), *(const float4*)(Whh1 + o + 4));
            }
        }
        {   f32x4 z = {0.f, 0.f, 0.f, 0.f}; *(f32x4*)(hb[1] + tid * 16) = z; }
        const f16* prow = pst + (size_t)brow * 512 * 256;

#define SPIN_J(need) do {                                                       \
        int mn_;                                                                \
        do {                                                                    \
            mn_ = 0x7fffffff;                                                   \
            _Pragma("unroll")                                                   \
            for (int i_ = 0; i_ < 8; ++i_) {                                    \
                int v_ = __hip_atomic_load(projf + gr * 8 + i_, __ATOMIC_RELAXED, \
                                           __HIP_MEMORY_SCOPE_AGENT);           \
                mn_ = v_ < mn_ ? v_ : mn_;                                      \
            }                                                                   \
        } while (mn_ < (need));                                                 \
        __builtin_amdgcn_fence(__ATOMIC_ACQUIRE, "agent");                      \
    } while (0)

        f16x4 pvE[2], pvO[2];
        SPIN_J(4);   // p[0..3] visible
#pragma unroll
        for (int tt = 0; tt < 2; ++tt) {
            pvE[tt] = *(const f16x4*)(prow + (size_t)0 * 256 + nb2 + tt * 16 + gl * 4);
            pvO[tt] = *(const f16x4*)(prow + (size_t)1 * 256 + nb2 + tt * 16 + gl * 4);
        }
        __syncthreads();

// consumer step S_: h1[S_] = tanh(p[S_] + Whh1 @ h1[S_-1]);
// reads hb[RD]=h1[S_-1], writes hb[WR]=h1[S_]; PV holds p[S_], reissued S_+2.
#define CBODY(PV, RD, WR, S_) do {                                              \
        if (((S_) & 7) == 1) {                                                  \
            const int nd_ = ((S_) + 10 < 512) ? (S_) + 10 : 512;                \
            SPIN_J(nd_);                                                        \
        }                                                                       \
        f16x8 bf0 = FRD(0, RD), bf1 = FRD(1, RD), bf2 = FRD(2, RD),             \
              bf3 = FRD(3, RD), bf4 = FRD(4, RD), bf5 = FRD(5, RD),             \
              bf6 = FRD(6, RD), bf7 = FRD(7, RD);                               \
        f32x4 aL[2], aH[2];                                                     \
        _Pragma("unroll")                                                       \
        for (int tt = 0; tt < 2; ++tt) {                                        \
            aL[tt] = cvt4f(PV[tt]);                                             \
            aH[tt][0] = 0.f; aH[tt][1] = 0.f; aH[tt][2] = 0.f; aH[tt][3] = 0.f; \
        }                                                                       \
        {   /* reissue PV <- p[S_+2] (anti-dep; vmcnt rides the barrier) */     \
            const int tr = ((S_) + 2 < 512) ? (S_) + 2 : 511;                   \
            _Pragma("unroll")                                                   \
            for (int tt = 0; tt < 2; ++tt)                                      \
                PV[tt] = *(const f16x4*)(prow + (size_t)tr * 256 + nb2 + tt * 16 + gl * 4); \
        }                                                                       \
        _Pragma("unroll")                                                       \
        for (int tt = 0; tt < 2; ++tt) {                                        \
            aL[tt] = MFMA(wC[tt][0], bf0, aL[tt]);                              \
            aH[tt] = MFMA(wC[tt][4], bf4, aH[tt]);                              \
            aL[tt] = MFMA(wC[tt][1], bf1, aL[tt]);                              \
            aH[tt] = MFMA(wC[tt][5], bf5, aH[tt]);                              \
            aL[tt] = MFMA(wC[tt][2], bf2, aL[tt]);                              \
            aH[tt] = MFMA(wC[tt][6], bf6, aH[tt]);                              \
            aL[tt] = MFMA(wC[tt][3], bf3, aL[tt]);                              \
            aH[tt] = MFMA(wC[tt][7], bf7, aH[tt]);                              \
        }                                                                       \
        _Pragma("unroll")                                                       \
        for (int tt = 0; tt < 2; ++tt) {                                        \
            f16x4 hv = tanh4(aL[tt], aH[tt]);                                   \
            *(f16x4*)(hb[WR] + wb2[tt]) = hv;                                   \
            if ((S_) == 511)                                                    \
                *(f16x4*)(h1out + (size_t)brow * H_ + nb2 + tt * 16 + gl * 4) = hv; \
        }                                                                       \
        if ((tid == 0) && (((S_) & 15) == 0))                                   \
            __hip_atomic_store(consf + gr, (S_), __ATOMIC_RELEASE,              \
                               __HIP_MEMORY_SCOPE_AGENT);                       \
        STEP_BAR();                                                             \
    } while (0)

        for (int s = 0; s < 512; s += 2) {
            CBODY(pvE, 1, 0, s);
            CBODY(pvO, 0, 1, s + 1);
        }
        if (tid == 0)
            __hip_atomic_store(consf + gr, 512, __ATOMIC_RELEASE, __HIP_MEMORY_SCOPE_AGENT);
#undef CBODY
#undef SPIN_J
    } else {
        // ================= PROJECTOR (no recurrence, no barriers) ==========
        f16x8 wP[2][8];
#pragma unroll
        for (int tt = 0; tt < 2; ++tt) {
            const int n = nb2 + tt * 16 + q;
#pragma unroll
            for (int kb = 0; kb < 8; ++kb) {
                const int o = n * H_ + kb * 32 + gl * 8;
                wP[tt][kb] = cvt8(*(const float4*)(Wih1 + o), *(const float4*)(Wih1 + o + 4));
            }
        }
        f32x4 bsP[2];
#pragma unroll
        for (int tt = 0; tt < 2; ++tt) {
            const int n = nb2 + tt * 16 + gl * 4;
            float4 x = *(const float4*)(bih1 + n);
            float4 y = *(const float4*)(bhh1 + n);
            bsP[tt][0] = x.x + y.x; bsP[tt][1] = x.y + y.y;
            bsP[tt][2] = x.z + y.z; bsP[tt][3] = x.w + y.w;
        }
        int* myflag = projf + gr * 8 + w;
        f16* pout = pst + (size_t)brow * 512 * 256 + nb2;

#define SPIN_R(need) do {                                                       \
        int mn_;                                                                \
        do {                                                                    \
            mn_ = 0x7fffffff;                                                   \
            _Pragma("unroll")                                                   \
            for (int i_ = 0; i_ < 8; ++i_) {                                    \
                int v_ = __hip_atomic_load(prodf + gr * 8 + i_, __ATOMIC_RELAXED, \
                                           __HIP_MEMORY_SCOPE_AGENT);           \
                mn_ = v_ < mn_ ? v_ : mn_;                                      \
            }                                                                   \
        } while (mn_ < (need));                                                 \
        __builtin_amdgcn_fence(__ATOMIC_ACQUIRE, "agent");                      \
    } while (0)

        f16x8 HFa[8], HFb[8];
        SPIN_R(8);   // ring slots 0..7 visible
        {
            const f16* r0 = ringg + q * 256 + gl * 8;
            const f16* r1 = ringg + (size_t)4096 + q * 256 + gl * 8;
#pragma unroll
            for (int kb = 0; kb < 8; ++kb) {
                HFa[kb] = *(const f16x8*)(r0 + kb * 32);
                HFb[kb] = *(const f16x8*)(r1 + kb * 32);
            }
        }

// one projector step S_: p[S_] from HF; reload HF <- ring[S_+2] (2-deep).
#define JBODY(HF, S_) do {                                                      \
        if (((S_) & 7) == 6) {   /* ring coverage for reloads up to S_+9 */     \
            const int nd_ = ((S_) + 12 < 516) ? (S_) + 12 : 516;                \
            SPIN_R(nd_);                                                        \
        }                                                                       \
        f32x4 pL[2], pH[2];                                                     \
        _Pragma("unroll")                                                       \
        for (int tt = 0; tt < 2; ++tt) {                                        \
            pL[tt] = bsP[tt];                                                   \
            pH[tt][0] = 0.f; pH[tt][1] = 0.f; pH[tt][2] = 0.f; pH[tt][3] = 0.f; \
            pL[tt] = MFMA(wP[tt][0], HF[0], pL[tt]);                            \
            pH[tt] = MFMA(wP[tt][4], HF[4], pH[tt]);                            \
            pL[tt] = MFMA(wP[tt][1], HF[1], pL[tt]);                            \
            pH[tt] = MFMA(wP[tt][5], HF[5], pH[tt]);                            \
            pL[tt] = MFMA(wP[tt][2], HF[2], pL[tt]);                            \
            pH[tt] = MFMA(wP[tt][6], HF[6], pH[tt]);                            \
            pL[tt] = MFMA(wP[tt][3], HF[3], pL[tt]);                            \
            pH[tt] = MFMA(wP[tt][7], HF[7], pH[tt]);                            \
        }                                                                       \
        {   /* reload HF <- ring[S_+2]: ~2 iterations of slack */               \
            const int nx = ((S_) + 2 < 512) ? (S_) + 2 : 511;                   \
            const f16* rp = ringg + (size_t)(nx & 127) * 4096 + q * 256 + gl * 8; \
            _Pragma("unroll")                                                   \
            for (int kb = 0; kb < 8; ++kb)                                      \
                HF[kb] = *(const f16x8*)(rp + kb * 32);                         \
        }                                                                       \
        _Pragma("unroll")                                                       \
        for (int tt = 0; tt < 2; ++tt)                                          \
            *(f16x4*)(pout + (size_t)(S_) * 256 + tt * 16 + gl * 4)             \
                = pack4(pL[tt], pH[tt]);                                        \
        if ((((S_) & 7) == 7) && lane == 0)                                     \
            __hip_atomic_store(myflag, (S_) + 1, __ATOMIC_RELEASE,              \
                               __HIP_MEMORY_SCOPE_AGENT);                       \
    } while (0)

        for (int s = 0; s < 512; s += 2) {
            JBODY(HFa, s);
            JBODY(HFb, s + 1);
        }
#undef JBODY
#undef SPIN_R
    }
#undef FRD
#undef STEP_BAR
}

// ---------------------------------------------------------------------------
// K3: out[b][v] = sum_k h1[b][k] * Wout[v][k] + bout[v].  fp32 out.
// ---------------------------------------------------------------------------
__global__ __launch_bounds__(512) void k_out(
    const f16* __restrict__ h1, const float* __restrict__ Wout,
    const float* __restrict__ bout, float* __restrict__ out)
{
    __shared__ char Hl[256 * 512];
    const int tid = threadIdx.x;
    {
        const int m = tid >> 1, half = tid & 1;
#pragma unroll
        for (int i = 0; i < 16; ++i) {
            const int blk = half * 16 + i;
            f16x8 v = *(const f16x8*)(h1 + m * H_ + blk * 8);
            *(f16x8*)(Hl + m * 512 + ((blk ^ (m & 7)) << 4)) = v;
        }
    }
    __syncthreads();
    const int lane = tid & 63, w = tid >> 6;
    const int q = lane & 15, g = lane >> 4;
    const int v0 = blockIdx.x * 80;
    f32x4 acc[5][2];
#pragma unroll
    for (int vt = 0; vt < 5; ++vt) {
        float4 bo = *(const float4*)(bout + v0 + vt * 16 + g * 4);
#pragma unroll
        for (int bt = 0; bt < 2; ++bt) {
            acc[vt][bt][0] = bo.x; acc[vt][bt][1] = bo.y;
            acc[vt][bt][2] = bo.z; acc[vt][bt][3] = bo.w;
        }
    }
#pragma unroll
    for (int kb = 0; kb < 8; ++kb) {
        f16x8 bf[2];
#pragma unroll
        for (int bt = 0; bt < 2; ++bt) {
            const int mrow = (w * 2 + bt) * 16 + q;
            bf[bt] = *(const f16x8*)(Hl + mrow * 512 + (((kb * 4 + g) ^ (mrow & 7)) << 4));
        }
#pragma unroll
        for (int vt = 0; vt < 5; ++vt) {
            const size_t vrow = v0 + vt * 16 + q;
            float4 a = *(const float4*)(Wout + vrow * H_ + kb * 32 + g * 8);
            float4 b = *(const float4*)(Wout + vrow * H_ + kb * 32 + g * 8 + 4);
            f16x8 af = cvt8(a, b);
#pragma unroll
            for (int bt = 0; bt < 2; ++bt)
                acc[vt][bt] = MFMA(af, bf[bt], acc[vt][bt]);
        }
    }
#pragma unroll
    for (int vt = 0; vt < 5; ++vt)
#pragma unroll
        for (int bt = 0; bt < 2; ++bt) {
            const int b = (w * 2 + bt) * 16 + q;
            const int v = v0 + vt * 16 + g * 4;
            float4 o = {acc[vt][bt][0], acc[vt][bt][1], acc[vt][bt][2], acc[vt][bt][3]};
            *(float4*)(out + (size_t)b * V_ + v) = o;
        }
}

extern "C" void kernel_launch(void* const* d_in, const int* in_sizes, int n_in,
                              void* d_out, int out_size, void* d_ws, size_t ws_size,
                              hipStream_t stream) {
    (void)in_sizes; (void)n_in; (void)out_size; (void)ws_size;
    const int*   batch = (const int*)  d_in[0];
    const float* feat  = (const float*)d_in[1];
    const float* Wih0  = (const float*)d_in[2];
    const float* Whh0  = (const float*)d_in[3];
    const float* bih0  = (const float*)d_in[4];
    const float* bhh0  = (const float*)d_in[5];
    const float* Wih1  = (const float*)d_in[6];
    const float* Whh1  = (const float*)d_in[7];
    const float* bih1  = (const float*)d_in[8];
    const float* bhh1  = (const float*)d_in[9];
    const float* Wout  = (const float*)d_in[10];
    const float* bout  = (const float*)d_in[11];
    float* out = (float*)d_out;

    // d_out scratch (dead before k_out writes):
    //   [0, 25.6MB)     T        vocab projection table (f16)
    //   [27MB, 43.8MB)  h0ring   16 groups x 128 slots x 16 x 256 f16
    //   [48MB, +2KB)    flags    prodf[16][8] + consf[16] + projf[16][8]
    f16* T      = (f16*)d_out;
    f16* h0ring = (f16*)((char*)d_out + 27000000);
    int* flags  = (int*)((char*)d_out + 48000000);
    // d_ws: pst 67.1MB + h1out 128KB
    f16* pst    = (f16*)d_ws;
    f16* h1out  = (f16*)((char*)d_ws + (size_t)B_ * S_ * H_ * 2);

    k_init_flags<<<dim3(1), dim3(512), 0, stream>>>(flags);
    k_vocab_proj<<<dim3(V_ / 16), dim3(512), 0, stream>>>(feat, Wih0, bih0, bhh0, T);
    k_rnn3p<<<dim3(48), dim3(512), 0, stream>>>(T, batch, Whh0, Wih1, bih1, bhh1,
                                                Whh1, h0ring, pst, flags, h1out);
    k_out<<<dim3(625), dim3(512), 0, stream>>>(h1out, Wout, bout, out);
}

// Round 17
// 860.694 us; speedup vs baseline: 1.6986x; 1.6986x over previous
//
#include <hip/hip_runtime.h>

#define B_ 256
#define S_ 512
#define V_ 50000
#define F_ 64
#define H_ 256

typedef _Float16 f16;
typedef _Float16 f16x2 __attribute__((ext_vector_type(2)));
typedef _Float16 f16x4 __attribute__((ext_vector_type(4)));
typedef _Float16 f16x8 __attribute__((ext_vector_type(8)));
typedef float f32x4 __attribute__((ext_vector_type(4)));

#define MFMA(a, b, c) __builtin_amdgcn_mfma_f32_16x16x32_f16((a), (b), (c), 0, 0, 0)

__device__ __forceinline__ f16x8 cvt8(const float4 a, const float4 b) {
    f16x8 v;
    v[0] = (f16)a.x; v[1] = (f16)a.y; v[2] = (f16)a.z; v[3] = (f16)a.w;
    v[4] = (f16)b.x; v[5] = (f16)b.y; v[6] = (f16)b.z; v[7] = (f16)b.w;
    return v;
}

// tanh(x) = 1 - 2/(1+e^2x); IEEE-safe at +/-inf.
__device__ __forceinline__ float fast_tanh(float x) {
    float e = __expf(2.f * x);
    float r = __builtin_amdgcn_rcpf(e + 1.f);
    return __builtin_fmaf(-2.f, r, 1.f);
}

__device__ __forceinline__ f32x4 cvt4f(const f16x4 v) {
    f32x4 r; r[0] = (float)v[0]; r[1] = (float)v[1]; r[2] = (float)v[2]; r[3] = (float)v[3];
    return r;
}
__device__ __forceinline__ f16x4 pack4s(const f32x4 a) {
    f16x4 r; r[0] = (f16)a[0]; r[1] = (f16)a[1]; r[2] = (f16)a[2]; r[3] = (f16)a[3];
    return r;
}
__device__ __forceinline__ f16x4 tanh4(const f32x4 a, const f32x4 b) {
    f16x4 r;
#pragma unroll
    for (int i = 0; i < 4; ++i) r[i] = (f16)fast_tanh(a[i] + b[i]);
    return r;
}

// ---------------------------------------------------------------------------
// K0: zero producer flags [16][8] + consumer flags [16] (every replay).
// ---------------------------------------------------------------------------
__global__ void k_init_flags(int* flags) {
    if (threadIdx.x < 256) flags[threadIdx.x] = 0;
}

// ---------------------------------------------------------------------------
// K1: T[v][n] = sum_f feat[v][f] * Wih0[n][f] + (bih0[n]+bhh0[n]); f16 out.
// ---------------------------------------------------------------------------
__global__ __launch_bounds__(512) void k_vocab_proj(
    const float* __restrict__ feat, const float* __restrict__ Wih,
    const float* __restrict__ bi, const float* __restrict__ bh,
    f16* __restrict__ T)
{
    __shared__ char Wl[256 * 128];
    __shared__ char Xl[16 * 128];
    const int tid = threadIdx.x;
    {
        const int n = tid >> 1, k0 = (tid & 1) << 5;
#pragma unroll
        for (int k = k0; k < k0 + 32; k += 8) {
            float4 a = *(const float4*)(Wih + n * F_ + k);
            float4 b = *(const float4*)(Wih + n * F_ + k + 4);
            *(f16x8*)(Wl + n * 128 + (((k >> 3) ^ (n & 7)) << 4)) = cvt8(a, b);
        }
    }
    const int v0 = blockIdx.x * 16;
    {
        const int m = tid >> 5, k = (tid & 31) << 1;
        float2 a = *(const float2*)(feat + (v0 + m) * F_ + k);
        f16x2 v; v[0] = (f16)a.x; v[1] = (f16)a.y;
        *(f16x2*)(Xl + m * 128 + ((((k >> 3) ^ (m & 7)) << 4) | ((k & 7) << 1))) = v;
    }
    __syncthreads();
    const int lane = tid & 63, w = tid >> 6;
    const int q = lane & 15, g = lane >> 4;
#pragma unroll
    for (int nt = 0; nt < 2; ++nt) {
        const int n0 = w * 32 + nt * 16;
        const int nrow = n0 + q;
        float4 b1 = *(const float4*)(bi + n0 + g * 4);
        float4 b2 = *(const float4*)(bh + n0 + g * 4);
        f32x4 acc = {b1.x + b2.x, b1.y + b2.y, b1.z + b2.z, b1.w + b2.w};
#pragma unroll
        for (int kb = 0; kb < 2; ++kb) {
            f16x8 a = *(const f16x8*)(Wl + nrow * 128 + (((kb * 4 + g) ^ (nrow & 7)) << 4));
            f16x8 b = *(const f16x8*)(Xl + q * 128 + (((kb * 4 + g) ^ (q & 7)) << 4));
            acc = MFMA(a, b, acc);
        }
        f16x4 o; o[0] = (f16)acc[0]; o[1] = (f16)acc[1]; o[2] = (f16)acc[2]; o[3] = (f16)acc[3];
        *(f16x4*)(T + (size_t)(v0 + q) * H_ + n0 + g * 4) = o;
    }
}

// ---------------------------------------------------------------------------
// K2: heterogeneous-role split RNN, 32 WGs x 512 thr (8 waves = 2/SIMD).
// EXACT R12 configuration (best verified: ~747us kernel, ~864us total;
// reproduced twice). All structural neighbors regressed (R13/R14/R16).
//   WGs 0-15  PRODUCER: pure recur0 (8-wave 2tt shape, 16 MFMA/wave/step).
//     h0_t -> LDS dbuf AND 128-slot global ring. Per-wave flag (release)
//     every 8 steps; back-pressure vs consumer every 16.
//   WGs 16-31 CONSUMER: 8 waves, TWO ROLES on each SIMD:
//     waves 0-3 (C): recur1, 4tt, 32 MFMA; h1 LDS dbuf; p from pb LDS.
//     waves 4-7 (P): p_s = b1 + Wih1 @ h0_s, 4tt, 32 MFMA; B-operand = h0
//       ring fragments held in registers (HF), reloaded each step with a
//       full step of slack; p -> pb LDS dbuf (1-step skew to C).
//   One lgkm-only barrier per step for all 8 waves.
// ---------------------------------------------------------------------------
__global__ __launch_bounds__(512) __attribute__((amdgpu_waves_per_eu(2, 2)))
void k_rnn2(
    const f16* __restrict__ T, const int* __restrict__ idx,
    const float* __restrict__ Whh0, const float* __restrict__ Wih1,
    const float* __restrict__ bih1, const float* __restrict__ bhh1,
    const float* __restrict__ Whh1,
    f16* __restrict__ h0ring, int* flags, f16* __restrict__ h1out)
{
    __shared__ char hb[2][8192];   // producer: h0 dbuf | consumer: h1 dbuf
    __shared__ char pb[2][8192];   // consumer: p dbuf (f16, swizzled)
    const int wg = blockIdx.x;
    const int tid = threadIdx.x, lane = tid & 63, w = tid >> 6;
    const int q = lane & 15, gl = lane >> 4;
    const int swz = (q & 7) << 4;

    int rbase[2];
#pragma unroll
    for (int p2 = 0; p2 < 2; ++p2)
        rbase[p2] = q * 512 + ((p2 * 64 + gl * 16) ^ swz);

    int* prodf = flags;          // [16][8] per-wave producer flags
    int* consf = flags + 128;    // [16] consumer progress
    const int gr = (wg < 16) ? wg : wg - 16;
    const int brow = gr * 16 + q;
    f16* ringg = h0ring + ((size_t)gr << 19);   // 128 slots x 4096 f16

#define FRD(kb_, RD_) (*(const f16x8*)(hb[RD_] + rbase[(kb_) & 1] + (((kb_) >> 1) * 128)))
#define STEP_BAR() do { \
        asm volatile("s_waitcnt lgkmcnt(0)" ::: "memory"); \
        __builtin_amdgcn_s_barrier(); \
    } while (0)

    if (wg < 16) {
        // ================= PRODUCER (8 waves, 2tt, pure recur0) ============
        const int nb2 = w * 32;
        int wb2[2];
#pragma unroll
        for (int tt = 0; tt < 2; ++tt)
            wb2[tt] = q * 512 + (((nb2 + tt * 16 + gl * 4) * 2) ^ swz);

        f16x8 wA[2][8];
#pragma unroll
        for (int tt = 0; tt < 2; ++tt) {
            const int n = nb2 + tt * 16 + q;
#pragma unroll
            for (int kb = 0; kb < 8; ++kb) {
                const int o = n * H_ + kb * 32 + gl * 8;
                wA[tt][kb] = cvt8(*(const float4*)(Whh0 + o), *(const float4*)(Whh0 + o + 4));
            }
        }
        {   f32x4 z = {0.f, 0.f, 0.f, 0.f}; *(f32x4*)(hb[1] + tid * 16) = z; }
        const int* idxr = idx + brow * S_;
        int* myflag = prodf + gr * 8 + w;
        f16x4 xa[2], xb[2];
        {
            const size_t r0 = (size_t)idxr[0] * H_, r1 = (size_t)idxr[1] * H_;
#pragma unroll
            for (int tt = 0; tt < 2; ++tt) {
                xa[tt] = *(const f16x4*)(T + r0 + nb2 + tt * 16 + gl * 4);
                xb[tt] = *(const f16x4*)(T + r1 + nb2 + tt * 16 + gl * 4);
            }
        }
        int iA = idxr[2], iB = idxr[3];
        __syncthreads();

#define PBODY(XV, ID, RD, WR, T_) do {                                          \
        if (((T_) & 15) == 0) {   /* ring back-pressure (margin 96 < 128) */    \
            int v_;                                                             \
            do { v_ = __hip_atomic_load(consf + gr, __ATOMIC_RELAXED,           \
                                        __HIP_MEMORY_SCOPE_AGENT);              \
            } while ((T_) - v_ > 96);                                           \
        }                                                                       \
        f16x8 bf0 = FRD(0, RD), bf1 = FRD(1, RD), bf2 = FRD(2, RD),             \
              bf3 = FRD(3, RD), bf4 = FRD(4, RD), bf5 = FRD(5, RD),             \
              bf6 = FRD(6, RD), bf7 = FRD(7, RD);                               \
        f32x4 aL[2], aH[2];                                                     \
        _Pragma("unroll")                                                       \
        for (int tt = 0; tt < 2; ++tt) {                                        \
            aL[tt] = cvt4f(XV[tt]);                                             \
            aH[tt][0] = 0.f; aH[tt][1] = 0.f; aH[tt][2] = 0.f; aH[tt][3] = 0.f; \
        }                                                                       \
        /* flag BEFORE new loads: release drains only old stores */            \
        if ((((T_) & 7) == 0) && lane == 0)                                     \
            __hip_atomic_store(myflag, (T_), __ATOMIC_RELEASE,                  \
                               __HIP_MEMORY_SCOPE_AGENT);                       \
        {                                                                       \
            const size_t rr = (size_t)ID * H_;                                  \
            _Pragma("unroll")                                                   \
            for (int tt = 0; tt < 2; ++tt)                                      \
                XV[tt] = *(const f16x4*)(T + rr + nb2 + tt * 16 + gl * 4);      \
            const int t4 = ((T_) + 4 < S_) ? (T_) + 4 : S_ - 1;                 \
            ID = idxr[t4];                                                      \
        }                                                                       \
        _Pragma("unroll")                                                       \
        for (int tt = 0; tt < 2; ++tt) {                                        \
            aL[tt] = MFMA(wA[tt][0], bf0, aL[tt]);                              \
            aH[tt] = MFMA(wA[tt][4], bf4, aH[tt]);                              \
            aL[tt] = MFMA(wA[tt][1], bf1, aL[tt]);                              \
            aH[tt] = MFMA(wA[tt][5], bf5, aH[tt]);                              \
            aL[tt] = MFMA(wA[tt][2], bf2, aL[tt]);                              \
            aH[tt] = MFMA(wA[tt][6], bf6, aH[tt]);                              \
            aL[tt] = MFMA(wA[tt][3], bf3, aL[tt]);                              \
            aH[tt] = MFMA(wA[tt][7], bf7, aH[tt]);                              \
        }                                                                       \
        {                                                                       \
            f16* rp = ringg + (size_t)((T_) & 127) * 4096 + q * 256 + nb2;      \
            _Pragma("unroll")                                                   \
            for (int tt = 0; tt < 2; ++tt) {                                    \
                f16x4 hv = tanh4(aL[tt], aH[tt]);                               \
                *(f16x4*)(hb[WR] + wb2[tt]) = hv;                               \
                *(f16x4*)(rp + tt * 16 + gl * 4) = hv;                          \
            }                                                                   \
        }                                                                       \
        STEP_BAR();                                                             \
    } while (0)

        // peel t=0 (from zero state)
        {
            f16x8 bf0 = FRD(0, 1), bf1 = FRD(1, 1), bf2 = FRD(2, 1), bf3 = FRD(3, 1),
                  bf4 = FRD(4, 1), bf5 = FRD(5, 1), bf6 = FRD(6, 1), bf7 = FRD(7, 1);
            f32x4 aL[2], aH[2];
#pragma unroll
            for (int tt = 0; tt < 2; ++tt) {
                aL[tt] = cvt4f(xa[tt]);
                aH[tt][0] = 0.f; aH[tt][1] = 0.f; aH[tt][2] = 0.f; aH[tt][3] = 0.f;
            }
            {
                const size_t rr = (size_t)iA * H_;
#pragma unroll
                for (int tt = 0; tt < 2; ++tt)
                    xa[tt] = *(const f16x4*)(T + rr + nb2 + tt * 16 + gl * 4);
                iA = idxr[4];
            }
#pragma unroll
            for (int tt = 0; tt < 2; ++tt) {
                aL[tt] = MFMA(wA[tt][0], bf0, aL[tt]);
                aH[tt] = MFMA(wA[tt][4], bf4, aH[tt]);
                aL[tt] = MFMA(wA[tt][1], bf1, aL[tt]);
                aH[tt] = MFMA(wA[tt][5], bf5, aH[tt]);
                aL[tt] = MFMA(wA[tt][2], bf2, aL[tt]);
                aH[tt] = MFMA(wA[tt][6], bf6, aH[tt]);
                aL[tt] = MFMA(wA[tt][3], bf3, aL[tt]);
                aH[tt] = MFMA(wA[tt][7], bf7, aH[tt]);
            }
            f16* rp = ringg + q * 256 + nb2;
#pragma unroll
            for (int tt = 0; tt < 2; ++tt) {
                f16x4 hv = tanh4(aL[tt], aH[tt]);
                *(f16x4*)(hb[0] + wb2[tt]) = hv;
                *(f16x4*)(rp + tt * 16 + gl * 4) = hv;
            }
            STEP_BAR();
        }
        for (int t = 1; t < 511; t += 2) {
            PBODY(xb, iB, 0, 1, t);
            PBODY(xa, iA, 1, 0, t + 1);
        }
        PBODY(xb, iB, 0, 1, 511);
        if (lane == 0)
            __hip_atomic_store(myflag, 516, __ATOMIC_RELEASE, __HIP_MEMORY_SCOPE_AGENT);
#undef PBODY
    } else {
        // ================= CONSUMER (C-waves 0-3 + P-waves 4-7) ============
        const bool isC = (w < 4);
        const int nb4 = (isC ? w : w - 4) * 64;
        int xbase[4];
#pragma unroll
        for (int tt = 0; tt < 4; ++tt)
            xbase[tt] = q * 512 + (((nb4 + tt * 16 + gl * 4) * 2) ^ swz);

        // role weights: C -> Whh1, P -> Wih1 (4tt each, 128 regs)
        f16x8 wR[4][8];
        {
            const float* Wsrc = isC ? Whh1 : Wih1;
#pragma unroll
            for (int tt = 0; tt < 4; ++tt) {
                const int n = nb4 + tt * 16 + q;
#pragma unroll
                for (int kb = 0; kb < 8; ++kb) {
                    const int o = n * H_ + kb * 32 + gl * 8;
                    wR[tt][kb] = cvt8(*(const float4*)(Wsrc + o), *(const float4*)(Wsrc + o + 4));
                }
            }
        }
        f32x4 bs1[4];   // P only (bias); C ignores
#pragma unroll
        for (int tt = 0; tt < 4; ++tt) {
            const int n = nb4 + tt * 16 + gl * 4;
            float4 x = *(const float4*)(bih1 + n);
            float4 y = *(const float4*)(bhh1 + n);
            bs1[tt][0] = x.x + y.x; bs1[tt][1] = x.y + y.y;
            bs1[tt][2] = x.z + y.z; bs1[tt][3] = x.w + y.w;
        }
        {   // h1_{-1}=0 into hb[1]
            f32x4 z = {0.f, 0.f, 0.f, 0.f};
            *(f32x4*)(hb[1] + tid * 16) = z;
        }

#define SPIN(need) do {                                                         \
        int mn_;                                                                \
        do {                                                                    \
            mn_ = 0x7fffffff;                                                   \
            _Pragma("unroll")                                                   \
            for (int i_ = 0; i_ < 8; ++i_) {                                    \
                int v_ = __hip_atomic_load(prodf + gr * 8 + i_, __ATOMIC_RELAXED, \
                                           __HIP_MEMORY_SCOPE_AGENT);           \
                mn_ = v_ < mn_ ? v_ : mn_;                                      \
            }                                                                   \
        } while (mn_ < (need));                                                 \
        __builtin_amdgcn_fence(__ATOMIC_ACQUIRE, "agent");                      \
    } while (0)

        f16x8 HF[8];      // P: current ring fragments
        if (!isC) {
            SPIN(12);
            const f16* rp = ringg + q * 256 + gl * 8;
#pragma unroll
            for (int kb = 0; kb < 8; ++kb)
                HF[kb] = *(const f16x8*)(rp + kb * 32);
        }
        __syncthreads();

// one consumer step s: P computes p[s] -> pb[WRP]; C computes h1[s-1]
// (reads p[s-1] from pb[RDP], h1[s-2] fragments from hb[RDH], writes hb[WRH])
#define SBODY(WRP, RDP, WRH, RDH, S_) do {                                      \
        if (isC) {                                                              \
            f16x8 cf0 = FRD(0, RDH), cf1 = FRD(1, RDH), cf2 = FRD(2, RDH),      \
                  cf3 = FRD(3, RDH), cf4 = FRD(4, RDH), cf5 = FRD(5, RDH),      \
                  cf6 = FRD(6, RDH), cf7 = FRD(7, RDH);                         \
            f32x4 cL[4], cH[4];                                                 \
            _Pragma("unroll")                                                   \
            for (int tt = 0; tt < 4; ++tt) {                                    \
                f16x4 pv = *(const f16x4*)(pb[RDP] + xbase[tt]);                \
                cL[tt] = cvt4f(pv);                                             \
                cH[tt][0] = 0.f; cH[tt][1] = 0.f; cH[tt][2] = 0.f; cH[tt][3] = 0.f; \
            }                                                                   \
            _Pragma("unroll")                                                   \
            for (int tt = 0; tt < 4; ++tt) {                                    \
                cL[tt] = MFMA(wR[tt][0], cf0, cL[tt]);                          \
                cH[tt] = MFMA(wR[tt][4], cf4, cH[tt]);                          \
                cL[tt] = MFMA(wR[tt][1], cf1, cL[tt]);                          \
                cH[tt] = MFMA(wR[tt][5], cf5, cH[tt]);                          \
                cL[tt] = MFMA(wR[tt][2], cf2, cL[tt]);                          \
                cH[tt] = MFMA(wR[tt][6], cf6, cH[tt]);                          \
                cL[tt] = MFMA(wR[tt][3], cf3, cL[tt]);                          \
                cH[tt] = MFMA(wR[tt][7], cf7, cH[tt]);                          \
            }                                                                   \
            _Pragma("unroll")                                                   \
            for (int tt = 0; tt < 4; ++tt)                                      \
                *(f16x4*)(hb[WRH] + xbase[tt]) = tanh4(cL[tt], cH[tt]);         \
            if ((tid == 0) && (((S_) & 15) == 0))                               \
                __hip_atomic_store(consf + gr, (S_), __ATOMIC_RELEASE,          \
                                   __HIP_MEMORY_SCOPE_AGENT);                   \
        } else {                                                                \
            if (((S_) & 7) == 0) {                                              \
                const int nd_ = ((S_) + 12 < 512) ? (S_) + 12 : 512;            \
                SPIN(nd_);                                                      \
            }                                                                   \
            f32x4 pA[4];                                                        \
            _Pragma("unroll")                                                   \
            for (int tt = 0; tt < 4; ++tt) pA[tt] = bs1[tt];                    \
            _Pragma("unroll")                                                   \
            for (int kb = 0; kb < 8; ++kb) {                                    \
                _Pragma("unroll")                                               \
                for (int tt = 0; tt < 4; ++tt)                                  \
                    pA[tt] = MFMA(wR[tt][kb], HF[kb], pA[tt]);                  \
            }                                                                   \
            {   /* reload HF <- ring[s+1] (anti-dep; vmcnt rides the barrier) */\
                const int nx = ((S_) + 1 < 512) ? (S_) + 1 : 511;               \
                const f16* rp = ringg + (size_t)(nx & 127) * 4096 + q * 256 + gl * 8; \
                _Pragma("unroll")                                               \
                for (int kb = 0; kb < 8; ++kb)                                  \
                    HF[kb] = *(const f16x8*)(rp + kb * 32);                     \
            }                                                                   \
            _Pragma("unroll")                                                   \
            for (int tt = 0; tt < 4; ++tt)                                      \
                *(f16x4*)(pb[WRP] + xbase[tt]) = pack4s(pA[tt]);                \
        }                                                                       \
        STEP_BAR();                                                             \
    } while (0)

        // peel s=0: P only (p[0] -> pb[0])
        {
            if (!isC) {
                f32x4 pA[4];
#pragma unroll
                for (int tt = 0; tt < 4; ++tt) pA[tt] = bs1[tt];
#pragma unroll
                for (int kb = 0; kb < 8; ++kb) {
#pragma unroll
                    for (int tt = 0; tt < 4; ++tt)
                        pA[tt] = MFMA(wR[tt][kb], HF[kb], pA[tt]);
                }
                {
                    const f16* rp = ringg + 4096 + q * 256 + gl * 8;
#pragma unroll
                    for (int kb = 0; kb < 8; ++kb)
                        HF[kb] = *(const f16x8*)(rp + kb * 32);
                }
#pragma unroll
                for (int tt = 0; tt < 4; ++tt)
                    *(f16x4*)(pb[0] + xbase[tt]) = pack4s(pA[tt]);
            }
            STEP_BAR();
        }
        // main: s = 1..510 in parity pairs, then s=511
        for (int s = 1; s < 511; s += 2) {
            SBODY(1, 0, 0, 1, s);
            SBODY(0, 1, 1, 0, s + 1);
        }
        SBODY(1, 0, 0, 1, 511);
        // peel s=512: C only, tau=511 -> h1out
        if (isC) {
            f16x8 cf0 = FRD(0, 0), cf1 = FRD(1, 0), cf2 = FRD(2, 0), cf3 = FRD(3, 0),
                  cf4 = FRD(4, 0), cf5 = FRD(5, 0), cf6 = FRD(6, 0), cf7 = FRD(7, 0);
            f32x4 cL[4], cH[4];
#pragma unroll
            for (int tt = 0; tt < 4; ++tt) {
                f16x4 pv = *(const f16x4*)(pb[1] + xbase[tt]);
                cL[tt] = cvt4f(pv);
                cH[tt][0] = 0.f; cH[tt][1] = 0.f; cH[tt][2] = 0.f; cH[tt][3] = 0.f;
            }
#pragma unroll
            for (int tt = 0; tt < 4; ++tt) {
                cL[tt] = MFMA(wR[tt][0], cf0, cL[tt]);
                cH[tt] = MFMA(wR[tt][4], cf4, cH[tt]);
                cL[tt] = MFMA(wR[tt][1], cf1, cL[tt]);
                cH[tt] = MFMA(wR[tt][5], cf5, cH[tt]);
                cL[tt] = MFMA(wR[tt][2], cf2, cL[tt]);
                cH[tt] = MFMA(wR[tt][6], cf6, cH[tt]);
                cL[tt] = MFMA(wR[tt][3], cf3, cL[tt]);
                cH[tt] = MFMA(wR[tt][7], cf7, cH[tt]);
            }
#pragma unroll
            for (int tt = 0; tt < 4; ++tt)
                *(f16x4*)(h1out + (size_t)brow * H_ + nb4 + tt * 16 + gl * 4)
                    = tanh4(cL[tt], cH[tt]);
        }
#undef SBODY
#undef SPIN
    }
#undef FRD
#undef STEP_BAR
}

// ---------------------------------------------------------------------------
// K3: out[b][v] = sum_k h1[b][k] * Wout[v][k] + bout[v].  fp32 out.
// ---------------------------------------------------------------------------
__global__ __launch_bounds__(512) void k_out(
    const f16* __restrict__ h1, const float* __restrict__ Wout,
    const float* __restrict__ bout, float* __restrict__ out)
{
    __shared__ char Hl[256 * 512];
    const int tid = threadIdx.x;
    {
        const int m = tid >> 1, half = tid & 1;
#pragma unroll
        for (int i = 0; i < 16; ++i) {
            const int blk = half * 16 + i;
            f16x8 v = *(const f16x8*)(h1 + m * H_ + blk * 8);
            *(f16x8*)(Hl + m * 512 + ((blk ^ (m & 7)) << 4)) = v;
        }
    }
    __syncthreads();
    const int lane = tid & 63, w = tid >> 6;
    const int q = lane & 15, g = lane >> 4;
    const int v0 = blockIdx.x * 80;
    f32x4 acc[5][2];
#pragma unroll
    for (int vt = 0; vt < 5; ++vt) {
        float4 bo = *(const float4*)(bout + v0 + vt * 16 + g * 4);
#pragma unroll
        for (int bt = 0; bt < 2; ++bt) {
            acc[vt][bt][0] = bo.x; acc[vt][bt][1] = bo.y;
            acc[vt][bt][2] = bo.z; acc[vt][bt][3] = bo.w;
        }
    }
#pragma unroll
    for (int kb = 0; kb < 8; ++kb) {
        f16x8 bf[2];
#pragma unroll
        for (int bt = 0; bt < 2; ++bt) {
            const int mrow = (w * 2 + bt) * 16 + q;
            bf[bt] = *(const f16x8*)(Hl + mrow * 512 + (((kb * 4 + g) ^ (mrow & 7)) << 4));
        }
#pragma unroll
        for (int vt = 0; vt < 5; ++vt) {
            const size_t vrow = v0 + vt * 16 + q;
            float4 a = *(const float4*)(Wout + vrow * H_ + kb * 32 + g * 8);
            float4 b = *(const float4*)(Wout + vrow * H_ + kb * 32 + g * 8 + 4);
            f16x8 af = cvt8(a, b);
#pragma unroll
            for (int bt = 0; bt < 2; ++bt)
                acc[vt][bt] = MFMA(af, bf[bt], acc[vt][bt]);
        }
    }
#pragma unroll
    for (int vt = 0; vt < 5; ++vt)
#pragma unroll
        for (int bt = 0; bt < 2; ++bt) {
            const int b = (w * 2 + bt) * 16 + q;
            const int v = v0 + vt * 16 + g * 4;
            float4 o = {acc[vt][bt][0], acc[vt][bt][1], acc[vt][bt][2], acc[vt][bt][3]};
            *(float4*)(out + (size_t)b * V_ + v) = o;
        }
}

extern "C" void kernel_launch(void* const* d_in, const int* in_sizes, int n_in,
                              void* d_out, int out_size, void* d_ws, size_t ws_size,
                              hipStream_t stream) {
    (void)in_sizes; (void)n_in; (void)out_size; (void)ws_size;
    const int*   batch = (const int*)  d_in[0];
    const float* feat  = (const float*)d_in[1];
    const float* Wih0  = (const float*)d_in[2];
    const float* Whh0  = (const float*)d_in[3];
    const float* bih0  = (const float*)d_in[4];
    const float* bhh0  = (const float*)d_in[5];
    const float* Wih1  = (const float*)d_in[6];
    const float* Whh1  = (const float*)d_in[7];
    const float* bih1  = (const float*)d_in[8];
    const float* bhh1  = (const float*)d_in[9];
    const float* Wout  = (const float*)d_in[10];
    const float* bout  = (const float*)d_in[11];
    float* out = (float*)d_out;

    // d_out scratch (dead before k_out writes):
    //   [0, 25.6MB)     T        vocab projection table (f16)
    //   [27MB, 43.8MB)  h0ring   16 groups x 128 slots x 16 x 256 f16
    //   [48MB, +1KB)    flags    prodf[16][8] + consf[16]
    f16* T      = (f16*)d_out;
    f16* h0ring = (f16*)((char*)d_out + 27000000);
    int* flags  = (int*)((char*)d_out + 48000000);
    f16* h1out  = (f16*)d_ws;   // 128KB

    k_init_flags<<<dim3(1), dim3(256), 0, stream>>>(flags);
    k_vocab_proj<<<dim3(V_ / 16), dim3(512), 0, stream>>>(feat, Wih0, bih0, bhh0, T);
    k_rnn2<<<dim3(32), dim3(512), 0, stream>>>(T, batch, Whh0, Wih1, bih1, bhh1,
                                               Whh1, h0ring, flags, h1out);
    k_out<<<dim3(625), dim3(512), 0, stream>>>(h1out, Wout, bout, out);
}